// Round 1
// baseline (2892.297 us; speedup 1.0000x reference)
//
#include <hip/hip_runtime.h>
#include <math.h>

#define D_MODEL 256
#define NHEAD 8
#define DHEAD 32
#define FFDIM 2048
#define NLAYER 6
#define BATCH 4
#define SEQ 1022
#define NTOK 1024

// ---------------- embed: build h = concat(cls1, x[:idx], cls2, x[idx:]) + PE ----------------
__global__ __launch_bounds__(256) void embed_kernel(
    const float* __restrict__ x, const float* __restrict__ cls1,
    const float* __restrict__ cls2, const int* __restrict__ ind,
    float* __restrict__ h)
{
    int i = blockIdx.x * 256 + threadIdx.x;   // [B*1024*256)
    int d = i & 255;
    int pos = (i >> 8) & 1023;
    int b = i >> 18;
    int idx = ind[b];
    float v;
    if (pos == 0) v = cls1[d];
    else if (pos == idx + 1) v = cls2[d];
    else if (pos <= idx) v = x[(b * SEQ + pos - 1) * D_MODEL + d];
    else v = x[(b * SEQ + pos - 2) * D_MODEL + d];
    int p = d >> 1;
    float freq = expf(-(float)p * (logf(10000.0f) / 128.0f));
    float ang = (float)pos * freq;
    v += (d & 1) ? cosf(ang) : sinf(ang);
    h[i] = v;
}

// ---------------- generic NT GEMM: C[M,N] = A[M,K] @ W[N,K]^T + bias (+R) (relu?) ----------------
// 64x64 block tile, K-tile 32, 256 threads, 4x4 micro-tile.
#define GT 64
#define GKT 32

__global__ __launch_bounds__(256) void gemm_nt_kernel(
    const float* __restrict__ A, const float* __restrict__ W,
    const float* __restrict__ bias, const float* __restrict__ R,
    float* __restrict__ C, int M, int N, int K, int relu)
{
    __shared__ float As[GKT][GT + 4];   // stride 68 floats = 272B (16B aligned rows)
    __shared__ float Bs[GKT][GT + 4];
    int ntile = N / GT;
    int bx = blockIdx.x % ntile;
    int by = blockIdx.x / ntile;
    int tid = threadIdx.x;
    int tx = tid & 15, ty = tid >> 4;
    int row0 = by * GT, col0 = bx * GT;
    float acc[4][4] = {};
    for (int k0 = 0; k0 < K; k0 += GKT) {
        #pragma unroll
        for (int p = 0; p < 8; ++p) {
            int ii = tid + p * 256;
            int kk = ii & 31, r = ii >> 5;
            As[kk][r] = A[(row0 + r) * K + k0 + kk];
            Bs[kk][r] = W[(col0 + r) * K + k0 + kk];
        }
        __syncthreads();
        #pragma unroll
        for (int kk = 0; kk < GKT; ++kk) {
            const float4 av = *(const float4*)&As[kk][ty * 4];
            const float4 bv = *(const float4*)&Bs[kk][tx * 4];
            acc[0][0] += av.x * bv.x; acc[0][1] += av.x * bv.y;
            acc[0][2] += av.x * bv.z; acc[0][3] += av.x * bv.w;
            acc[1][0] += av.y * bv.x; acc[1][1] += av.y * bv.y;
            acc[1][2] += av.y * bv.z; acc[1][3] += av.y * bv.w;
            acc[2][0] += av.z * bv.x; acc[2][1] += av.z * bv.y;
            acc[2][2] += av.z * bv.z; acc[2][3] += av.z * bv.w;
            acc[3][0] += av.w * bv.x; acc[3][1] += av.w * bv.y;
            acc[3][2] += av.w * bv.z; acc[3][3] += av.w * bv.w;
        }
        __syncthreads();
    }
    #pragma unroll
    for (int i = 0; i < 4; ++i) {
        int r = row0 + ty * 4 + i;
        #pragma unroll
        for (int j = 0; j < 4; ++j) {
            int c = col0 + tx * 4 + j;
            float v = acc[i][j] + bias[c];
            if (R) v += R[r * N + c];
            if (relu) v = fmaxf(v, 0.0f);
            C[r * N + c] = v;
        }
    }
}

// ---------------- flash attention with two-segment block-diagonal mask ----------------
// grid: B*H*32 blocks (32 q-rows each), 256 threads (4 waves, 8 q-rows/wave, 8 lanes/row)
__global__ __launch_bounds__(256) void attn_kernel(
    const float* __restrict__ qkv, float* __restrict__ att,
    const int* __restrict__ ind)
{
    __shared__ float Ks[32][40];   // stride 160B: 16B-aligned rows, 2-way max conflicts
    __shared__ float Vs[32][40];
    int qt = blockIdx.x & 31;
    int hh = (blockIdx.x >> 5) & 7;
    int b = blockIdx.x >> 8;
    int idx = ind[b];
    int segEnd = NTOK - ind[4 + b];
    int tid = threadIdx.x;
    int wave = tid >> 6, lane = tid & 63;
    int qlw = lane >> 3, kg = lane & 7;
    int ql = wave * 8 + qlw;
    int q0 = qt * 32;
    int q = q0 + ql;
    bool v1q = (q <= idx);
    bool v2q = (q > idx) && (q < segEnd);
    const float scale = 0.17677669529663687f;   // 1/sqrt(32)

    float qr[32];
    {
        const float* qp = qkv + (b * NTOK + q) * 768 + hh * 32;
        #pragma unroll
        for (int d = 0; d < 32; ++d) qr[d] = qp[d] * scale;
    }
    float o[32];
    #pragma unroll
    for (int d = 0; d < 32; ++d) o[d] = 0.0f;
    float mrun = -1e30f, lsum = 0.0f;

    int kbeg = (q0 <= idx) ? 0 : (idx + 1);
    int kend = (q0 + 31 > idx) ? segEnd : (idx + 1);

    for (int k0 = (kbeg & ~31); k0 < kend; k0 += 32) {
        #pragma unroll
        for (int p = 0; p < 4; ++p) {
            int ii = tid + p * 256;
            int dd = ii & 31, rr = ii >> 5;
            const float* kp = qkv + (b * NTOK + k0 + rr) * 768 + 256 + hh * 32;
            Ks[rr][dd] = kp[dd];
            Vs[rr][dd] = kp[256 + dd];
        }
        __syncthreads();

        float sv[4]; bool okv[4];
        #pragma unroll
        for (int j = 0; j < 4; ++j) {
            int kl = kg * 4 + j;
            int k = k0 + kl;
            float a = 0.0f;
            #pragma unroll
            for (int d = 0; d < 32; ++d) a += qr[d] * Ks[kl][d];
            bool v1k = (k <= idx);
            bool v2k = (k > idx) && (k < segEnd);
            bool ok = (v1q && v1k) || (v2q && v2k);
            okv[j] = ok;
            sv[j] = ok ? a : -1e30f;
        }
        float mloc = fmaxf(fmaxf(sv[0], sv[1]), fmaxf(sv[2], sv[3]));
        mloc = fmaxf(mloc, __shfl_xor(mloc, 1));
        mloc = fmaxf(mloc, __shfl_xor(mloc, 2));
        mloc = fmaxf(mloc, __shfl_xor(mloc, 4));
        float mnew = fmaxf(mrun, mloc);
        float corr = __expf(mrun - mnew);
        float pj[4]; float psum = 0.0f;
        #pragma unroll
        for (int j = 0; j < 4; ++j) {
            pj[j] = okv[j] ? __expf(sv[j] - mnew) : 0.0f;
            psum += pj[j];
        }
        lsum = lsum * corr + psum;
        #pragma unroll
        for (int d = 0; d < 32; ++d) {
            float pv = pj[0] * Vs[kg * 4 + 0][d] + pj[1] * Vs[kg * 4 + 1][d]
                     + pj[2] * Vs[kg * 4 + 2][d] + pj[3] * Vs[kg * 4 + 3][d];
            o[d] = o[d] * corr + pv;
        }
        mrun = mnew;
        __syncthreads();
    }

    lsum += __shfl_xor(lsum, 1);
    lsum += __shfl_xor(lsum, 2);
    lsum += __shfl_xor(lsum, 4);
    float invl = (lsum > 0.0f) ? (1.0f / lsum) : 0.0f;

    float w0 = 0, w1 = 0, w2 = 0, w3 = 0;
    #pragma unroll
    for (int d = 0; d < 32; ++d) {
        float t = o[d];
        t += __shfl_xor(t, 1); t += __shfl_xor(t, 2); t += __shfl_xor(t, 4);
        if (kg == (d >> 2)) {   // d>>2, d&3 compile-time: static register select
            if ((d & 3) == 0) w0 = t;
            else if ((d & 3) == 1) w1 = t;
            else if ((d & 3) == 2) w2 = t;
            else w3 = t;
        }
    }
    float* op = att + (b * NTOK + q) * D_MODEL + hh * 32 + kg * 4;
    op[0] = w0 * invl; op[1] = w1 * invl; op[2] = w2 * invl; op[3] = w3 * invl;
}

// ---------------- LayerNorm over D=256 per row ----------------
__global__ __launch_bounds__(256) void ln_kernel(
    const float* __restrict__ X, const float* __restrict__ g,
    const float* __restrict__ bb, float* __restrict__ Y)
{
    __shared__ float red[8];
    int row = blockIdx.x;
    int tid = threadIdx.x;
    float x = X[row * 256 + tid];
    float s = x;
    #pragma unroll
    for (int off = 32; off >= 1; off >>= 1) s += __shfl_xor(s, off);
    if ((tid & 63) == 0) red[tid >> 6] = s;
    __syncthreads();
    float mu = (red[0] + red[1] + red[2] + red[3]) * (1.0f / 256.0f);
    float dv = x - mu;
    float s2 = dv * dv;
    #pragma unroll
    for (int off = 32; off >= 1; off >>= 1) s2 += __shfl_xor(s2, off);
    if ((tid & 63) == 0) red[4 + (tid >> 6)] = s2;
    __syncthreads();
    float var = (red[4] + red[5] + red[6] + red[7]) * (1.0f / 256.0f);
    float inv = 1.0f / sqrtf(var + 1e-5f);
    Y[row * 256 + tid] = dv * inv * g[tid] + bb[tid];
}

// ---------------- gather cls outputs ----------------
__global__ __launch_bounds__(256) void gather_kernel(
    const float* __restrict__ h, const int* __restrict__ ind, float* __restrict__ out)
{
    int b = blockIdx.x;
    int tid = threadIdx.x;
    out[(b * 2 + 0) * 256 + tid] = h[(b * NTOK + 0) * 256 + tid];
    out[(b * 2 + 1) * 256 + tid] = h[(b * NTOK + ind[b] + 1) * 256 + tid];
}

extern "C" void kernel_launch(void* const* d_in, const int* in_sizes, int n_in,
                              void* d_out, int out_size, void* d_ws, size_t ws_size,
                              hipStream_t stream)
{
    const float* x    = (const float*)d_in[0];
    const int*   ind  = (const int*)d_in[2];
    const float* cls1 = (const float*)d_in[3];
    const float* cls2 = (const float*)d_in[4];
    const float* Wqkv = (const float*)d_in[5];
    const float* bqkv = (const float*)d_in[6];
    const float* Wo   = (const float*)d_in[7];
    const float* bo   = (const float*)d_in[8];
    const float* g1   = (const float*)d_in[9];
    const float* be1  = (const float*)d_in[10];
    const float* W1   = (const float*)d_in[11];
    const float* bf1  = (const float*)d_in[12];
    const float* W2   = (const float*)d_in[13];
    const float* bf2  = (const float*)d_in[14];
    const float* g2   = (const float*)d_in[15];
    const float* be2  = (const float*)d_in[16];
    float* out = (float*)d_out;

    // workspace layout (floats): needs 14,680,064 floats = 58.7 MB
    float* ws  = (float*)d_ws;
    float* h   = ws;                       // 4096*256
    float* qkv = h   + 4096 * 256;         // 4096*768
    float* att = qkv + 4096 * 768;         // 4096*256
    float* tmp = att + 4096 * 256;         // 4096*256
    float* ff  = tmp + 4096 * 256;         // 4096*2048

    const int M = BATCH * NTOK;            // 4096

    embed_kernel<<<M, 256, 0, stream>>>(x, cls1, cls2, ind, h);

    for (int l = 0; l < NLAYER; ++l) {
        const float* Wqkv_l = Wqkv + (size_t)l * 768 * 256;
        const float* bqkv_l = bqkv + (size_t)l * 768;
        const float* Wo_l   = Wo   + (size_t)l * 256 * 256;
        const float* bo_l   = bo   + (size_t)l * 256;
        const float* g1_l   = g1   + (size_t)l * 256;
        const float* be1_l  = be1  + (size_t)l * 256;
        const float* W1_l   = W1   + (size_t)l * 2048 * 256;
        const float* bf1_l  = bf1  + (size_t)l * 2048;
        const float* W2_l   = W2   + (size_t)l * 256 * 2048;
        const float* bf2_l  = bf2  + (size_t)l * 256;
        const float* g2_l   = g2   + (size_t)l * 256;
        const float* be2_l  = be2  + (size_t)l * 256;

        // qkv = h @ Wqkv^T + bqkv
        gemm_nt_kernel<<<(M / GT) * (768 / GT), 256, 0, stream>>>(
            h, Wqkv_l, bqkv_l, nullptr, qkv, M, 768, 256, 0);
        // att = softmax(q k^T * scale + segment bias) v
        attn_kernel<<<BATCH * NHEAD * 32, 256, 0, stream>>>(qkv, att, ind);
        // tmp = att @ Wo^T + bo + h (residual)
        gemm_nt_kernel<<<(M / GT) * (256 / GT), 256, 0, stream>>>(
            att, Wo_l, bo_l, h, tmp, M, 256, 256, 0);
        // h = LN(tmp)
        ln_kernel<<<M, 256, 0, stream>>>(tmp, g1_l, be1_l, h);
        // ff = relu(h @ W1^T + b1)
        gemm_nt_kernel<<<(M / GT) * (2048 / GT), 256, 0, stream>>>(
            h, W1_l, bf1_l, nullptr, ff, M, 2048, 256, 1);
        // tmp = ff @ W2^T + b2 + h (residual)
        gemm_nt_kernel<<<(M / GT) * (256 / GT), 256, 0, stream>>>(
            ff, W2_l, bf2_l, h, tmp, M, 256, 2048, 0);
        // h = LN(tmp)
        ln_kernel<<<M, 256, 0, stream>>>(tmp, g2_l, be2_l, h);
    }

    gather_kernel<<<BATCH, 256, 0, stream>>>(h, ind, out);
}

// Round 2
// 1218.023 us; speedup vs baseline: 2.3746x; 2.3746x over previous
//
#include <hip/hip_runtime.h>
#include <hip/hip_bf16.h>
#include <math.h>

typedef __hip_bfloat16 bf16;
typedef short bf16x8 __attribute__((ext_vector_type(8)));
typedef float f32x4 __attribute__((ext_vector_type(4)));

#define D_MODEL 256
#define NTOK 1024
#define SEQ 1022
#define BATCH 4
#define NLAYER 6

// ---- async global->LDS 16B helper ----
__device__ inline void gload_lds16(const void* g, void* l) {
    __builtin_amdgcn_global_load_lds(
        (const __attribute__((address_space(1))) void*)g,
        (__attribute__((address_space(3))) void*)l, 16, 0, 0);
}

// ---------------- weight fp32 -> bf16 cast ----------------
__global__ __launch_bounds__(256) void cast_kernel(
    const float* __restrict__ in, bf16* __restrict__ out, int n)
{
    int i = (blockIdx.x * 256 + threadIdx.x) * 4;
    if (i >= n) return;
    f32x4 v = *(const f32x4*)(in + i);
    out[i + 0] = __float2bfloat16(v[0]);
    out[i + 1] = __float2bfloat16(v[1]);
    out[i + 2] = __float2bfloat16(v[2]);
    out[i + 3] = __float2bfloat16(v[3]);
}

// ---------------- embed: h = concat(cls1, x[:idx], cls2, x[idx:]) + PE ; also bf16 copy ----------------
__global__ __launch_bounds__(256) void embed_kernel(
    const float* __restrict__ x, const float* __restrict__ cls1,
    const float* __restrict__ cls2, const int* __restrict__ ind,
    float* __restrict__ h, bf16* __restrict__ hb)
{
    int i = blockIdx.x * 256 + threadIdx.x;
    int d = i & 255;
    int pos = (i >> 8) & 1023;
    int b = i >> 18;
    int idx = ind[b];
    float v;
    if (pos == 0) v = cls1[d];
    else if (pos == idx + 1) v = cls2[d];
    else if (pos <= idx) v = x[(b * SEQ + pos - 1) * D_MODEL + d];
    else v = x[(b * SEQ + pos - 2) * D_MODEL + d];
    int p = d >> 1;
    float freq = expf(-(float)p * (logf(10000.0f) / 128.0f));
    float ang = (float)pos * freq;
    v += (d & 1) ? cosf(ang) : sinf(ang);
    h[i] = v;
    hb[i] = __float2bfloat16(v);
}

// ---------------- bf16 MFMA NT GEMM: C[M,N] = A[M,K] @ W[N,K]^T + bias (+R) (relu?) ----------------
// wave grid 2x2; wave tile (MR*16) x (NR*16); block tile BM=MR*32, BN=NR*32; K-step 32.
template<int MR, int NR, int RELU, int HAS_RES, int WF32, int WBF16>
__global__ __launch_bounds__(256) void mfma_gemm(
    const bf16* __restrict__ A, const bf16* __restrict__ W,
    const float* __restrict__ bias, const float* __restrict__ R,
    float* __restrict__ Cf, bf16* __restrict__ Cb, int M, int N, int K)
{
    constexpr int BM = MR * 32, BN = NR * 32;
    constexpr int ACH = BM * 4;     // 16B chunks per A tile (4 per row of 32 bf16)
    constexpr int BCH = BN * 4;
    __shared__ bf16 As[2][BM * 32];
    __shared__ bf16 Bs[2][BN * 32];
    const int ntile = N / BN;
    const int bx = blockIdx.x % ntile, by = blockIdx.x / ntile;
    const int row0 = by * BM, col0 = bx * BN;
    const int tid = threadIdx.x, lane = tid & 63, wave = tid >> 6;
    const int wr = wave >> 1, wc = wave & 1;
    const int l15 = lane & 15, l4 = lane >> 4;

    f32x4 acc[MR][NR];
    #pragma unroll
    for (int m = 0; m < MR; ++m)
        #pragma unroll
        for (int n = 0; n < NR; ++n) acc[m][n] = (f32x4)0.0f;

    const int nk = K / 32;

    auto stage = [&](int buf, int t) {
        const int k0 = t * 32;
        #pragma unroll
        for (int p = 0; p < ACH / 256; ++p) {
            const int cbase = p * 256 + wave * 64;
            const int chunk = cbase + lane;
            const int r = chunk >> 2, c = chunk & 3;
            gload_lds16(A + (size_t)(row0 + r) * K + k0 + c * 8, &As[buf][cbase * 8]);
        }
        #pragma unroll
        for (int p = 0; p < BCH / 256; ++p) {
            const int cbase = p * 256 + wave * 64;
            const int chunk = cbase + lane;
            const int r = chunk >> 2, c = chunk & 3;
            gload_lds16(W + (size_t)(col0 + r) * K + k0 + c * 8, &Bs[buf][cbase * 8]);
        }
    };

    stage(0, 0);
    __syncthreads();
    int cur = 0;
    for (int t = 0; t < nk; ++t) {
        if (t + 1 < nk) stage(cur ^ 1, t + 1);
        bf16x8 af[MR], bfr[NR];
        #pragma unroll
        for (int m = 0; m < MR; ++m)
            af[m] = *(const bf16x8*)&As[cur][(wr * MR * 16 + m * 16 + l15) * 32 + l4 * 8];
        #pragma unroll
        for (int n = 0; n < NR; ++n)
            bfr[n] = *(const bf16x8*)&Bs[cur][(wc * NR * 16 + n * 16 + l15) * 32 + l4 * 8];
        #pragma unroll
        for (int m = 0; m < MR; ++m)
            #pragma unroll
            for (int n = 0; n < NR; ++n)
                acc[m][n] = __builtin_amdgcn_mfma_f32_16x16x32_bf16(af[m], bfr[n], acc[m][n], 0, 0, 0);
        __syncthreads();
        cur ^= 1;
    }

    #pragma unroll
    for (int m = 0; m < MR; ++m) {
        #pragma unroll
        for (int n = 0; n < NR; ++n) {
            const int col = col0 + wc * NR * 16 + n * 16 + l15;
            const float bv = bias[col];
            #pragma unroll
            for (int r = 0; r < 4; ++r) {
                const int row = row0 + wr * MR * 16 + m * 16 + l4 * 4 + r;
                float v = acc[m][n][r] + bv;
                if (HAS_RES) v += R[(size_t)row * N + col];
                if (RELU) v = fmaxf(v, 0.0f);
                if (WF32) Cf[(size_t)row * N + col] = v;
                if (WBF16) Cb[(size_t)row * N + col] = __float2bfloat16(v);
            }
        }
    }
}

// ---------------- flash attention, two-segment block-diagonal mask ----------------
// grid: B*H*32 (32 q-rows/block); 256 thr = 4 waves; wave = 8 q-rows x 8 k-owners.
// lane kg owns k = kg + 8j (strided) -> ds_read_b128 rows hit 4 distinct bank
// groups (2-way conflict = free), broadcast across the 8 q-lanes.
__global__ __launch_bounds__(256) void attn_kernel(
    const float* __restrict__ qkv, bf16* __restrict__ att, const int* __restrict__ ind)
{
    __shared__ float Ks[64][40];
    __shared__ float Vs[64][40];
    const int qt = blockIdx.x & 31;
    const int hh = (blockIdx.x >> 5) & 7;
    const int b  = blockIdx.x >> 8;
    const int idx = ind[b];
    const int segEnd = NTOK - ind[4 + b];
    const int tid = threadIdx.x, lane = tid & 63, wave = tid >> 6;
    const int qlw = lane >> 3, kg = lane & 7;
    const int q0 = qt * 32, q = q0 + wave * 8 + qlw;
    const bool v1q = (q <= idx);
    const bool v2q = (q > idx) && (q < segEnd);
    const float scale = 0.17677669529663687f;

    f32x4 qr[8];
    {
        const f32x4* qp = (const f32x4*)(qkv + (size_t)(b * NTOK + q) * 768 + hh * 32);
        #pragma unroll
        for (int c = 0; c < 8; ++c) qr[c] = qp[c] * scale;
    }
    f32x4 o4[8];
    #pragma unroll
    for (int c = 0; c < 8; ++c) o4[c] = (f32x4)0.0f;
    float mrun = -1e30f, lsum = 0.0f;

    const int kbeg = (q0 <= idx) ? 0 : (idx + 1);
    const int kend = (q0 + 31 > idx) ? segEnd : (idx + 1);

    for (int k0 = (kbeg & ~63); k0 < kend; k0 += 64) {
        #pragma unroll
        for (int p = 0; p < 2; ++p) {
            const int chunk = p * 256 + tid;            // 0..511
            const int rr = chunk >> 3, c = chunk & 7;
            const f32x4* src = (const f32x4*)(qkv + (size_t)(b * NTOK + k0 + rr) * 768 + 256 + hh * 32);
            *(f32x4*)&Ks[rr][c * 4] = src[c];
            *(f32x4*)&Vs[rr][c * 4] = src[64 + c];      // +256 floats = V block
        }
        __syncthreads();

        float pj[8]; bool okv[8];
        float mloc = -1e30f;
        #pragma unroll
        for (int j = 0; j < 8; ++j) {
            const int kl = kg + 8 * j;
            const int k = k0 + kl;
            const f32x4* kr = (const f32x4*)&Ks[kl][0];
            f32x4 a4 = qr[0] * kr[0];
            #pragma unroll
            for (int c = 1; c < 8; ++c) a4 += qr[c] * kr[c];
            float a = (a4[0] + a4[1]) + (a4[2] + a4[3]);
            const bool v1k = (k <= idx);
            const bool v2k = (k > idx) && (k < segEnd);
            okv[j] = (v1q && v1k) || (v2q && v2k);
            pj[j] = okv[j] ? a : -1e30f;
            mloc = fmaxf(mloc, pj[j]);
        }
        mloc = fmaxf(mloc, __shfl_xor(mloc, 1));
        mloc = fmaxf(mloc, __shfl_xor(mloc, 2));
        mloc = fmaxf(mloc, __shfl_xor(mloc, 4));
        const float mnew = fmaxf(mrun, mloc);
        const float corr = __expf(mrun - mnew);
        float psum = 0.0f;
        #pragma unroll
        for (int j = 0; j < 8; ++j) {
            pj[j] = okv[j] ? __expf(pj[j] - mnew) : 0.0f;
            psum += pj[j];
        }
        lsum = lsum * corr + psum;
        #pragma unroll
        for (int c = 0; c < 8; ++c) o4[c] *= corr;
        #pragma unroll
        for (int j = 0; j < 8; ++j) {
            const f32x4* vr = (const f32x4*)&Vs[kg + 8 * j][0];
            const float p = pj[j];
            #pragma unroll
            for (int c = 0; c < 8; ++c) o4[c] += p * vr[c];
        }
        mrun = mnew;
        __syncthreads();
    }

    lsum += __shfl_xor(lsum, 1);
    lsum += __shfl_xor(lsum, 2);
    lsum += __shfl_xor(lsum, 4);
    const float invl = (lsum > 0.0f) ? (1.0f / lsum) : 0.0f;

    float w[4] = {0, 0, 0, 0};
    #pragma unroll
    for (int c = 0; c < 8; ++c) {
        #pragma unroll
        for (int e = 0; e < 4; ++e) {
            float t = o4[c][e];
            t += __shfl_xor(t, 1);
            t += __shfl_xor(t, 2);
            t += __shfl_xor(t, 4);
            if (kg == c) w[e] = t;
        }
    }
    bf16* op = att + (size_t)(b * NTOK + q) * 256 + hh * 32 + kg * 4;
    #pragma unroll
    for (int e = 0; e < 4; ++e) op[e] = __float2bfloat16(w[e] * invl);
}

// ---------------- LayerNorm over D=256 per row, fp32 + bf16 outputs ----------------
__global__ __launch_bounds__(256) void ln_kernel(
    const float* __restrict__ X, const float* __restrict__ g,
    const float* __restrict__ bb, float* __restrict__ Y, bf16* __restrict__ Yb)
{
    __shared__ float red[8];
    int row = blockIdx.x;
    int tid = threadIdx.x;
    float x = X[row * 256 + tid];
    float s = x;
    #pragma unroll
    for (int off = 32; off >= 1; off >>= 1) s += __shfl_xor(s, off);
    if ((tid & 63) == 0) red[tid >> 6] = s;
    __syncthreads();
    float mu = (red[0] + red[1] + red[2] + red[3]) * (1.0f / 256.0f);
    float dv = x - mu;
    float s2 = dv * dv;
    #pragma unroll
    for (int off = 32; off >= 1; off >>= 1) s2 += __shfl_xor(s2, off);
    if ((tid & 63) == 0) red[4 + (tid >> 6)] = s2;
    __syncthreads();
    float var = (red[4] + red[5] + red[6] + red[7]) * (1.0f / 256.0f);
    float inv = 1.0f / sqrtf(var + 1e-5f);
    float y = dv * inv * g[tid] + bb[tid];
    Y[row * 256 + tid] = y;
    Yb[row * 256 + tid] = __float2bfloat16(y);
}

// ---------------- gather cls outputs ----------------
__global__ __launch_bounds__(256) void gather_kernel(
    const float* __restrict__ h, const int* __restrict__ ind, float* __restrict__ out)
{
    int b = blockIdx.x;
    int tid = threadIdx.x;
    out[(b * 2 + 0) * 256 + tid] = h[(b * NTOK + 0) * 256 + tid];
    out[(b * 2 + 1) * 256 + tid] = h[(b * NTOK + ind[b] + 1) * 256 + tid];
}

extern "C" void kernel_launch(void* const* d_in, const int* in_sizes, int n_in,
                              void* d_out, int out_size, void* d_ws, size_t ws_size,
                              hipStream_t stream)
{
    const float* x    = (const float*)d_in[0];
    const int*   ind  = (const int*)d_in[2];
    const float* cls1 = (const float*)d_in[3];
    const float* cls2 = (const float*)d_in[4];
    const float* Wqkv = (const float*)d_in[5];
    const float* bqkv = (const float*)d_in[6];
    const float* Wo   = (const float*)d_in[7];
    const float* bo   = (const float*)d_in[8];
    const float* g1   = (const float*)d_in[9];
    const float* be1  = (const float*)d_in[10];
    const float* W1   = (const float*)d_in[11];
    const float* bf1  = (const float*)d_in[12];
    const float* W2   = (const float*)d_in[13];
    const float* bf2  = (const float*)d_in[14];
    const float* g2   = (const float*)d_in[15];
    const float* be2  = (const float*)d_in[16];
    float* out = (float*)d_out;

    // ---- workspace layout (57.67 MB) ----
    float* ws   = (float*)d_ws;
    float* h    = ws;                       // 1,048,576 f32
    float* qkv  = h + 1048576;              // 3,145,728 f32
    float* tmp  = qkv + 3145728;            // 1,048,576 f32
    bf16* hb    = (bf16*)(tmp + 1048576);   // 1,048,576 bf16
    bf16* attb  = hb + 1048576;             // 1,048,576
    bf16* ffb   = attb + 1048576;           // 8,388,608
    bf16* wqkvb = ffb + 8388608;            // 1,179,648
    bf16* wob   = wqkvb + 1179648;          // 393,216
    bf16* w1b   = wob + 393216;             // 3,145,728
    bf16* w2b   = w1b + 3145728;            // 3,145,728

    const int M = BATCH * NTOK;             // 4096

    // weight casts (once per call)
    cast_kernel<<<1152, 256, 0, stream>>>(Wqkv, wqkvb, 1179648);
    cast_kernel<<<384,  256, 0, stream>>>(Wo,   wob,   393216);
    cast_kernel<<<3072, 256, 0, stream>>>(W1,   w1b,   3145728);
    cast_kernel<<<3072, 256, 0, stream>>>(W2,   w2b,   3145728);

    embed_kernel<<<M, 256, 0, stream>>>(x, cls1, cls2, ind, h, hb);

    for (int l = 0; l < NLAYER; ++l) {
        const bf16*  Wqkv_l = wqkvb + (size_t)l * 768 * 256;
        const float* bqkv_l = bqkv + (size_t)l * 768;
        const bf16*  Wo_l   = wob + (size_t)l * 256 * 256;
        const float* bo_l   = bo + (size_t)l * 256;
        const float* g1_l   = g1 + (size_t)l * 256;
        const float* be1_l  = be1 + (size_t)l * 256;
        const bf16*  W1_l   = w1b + (size_t)l * 2048 * 256;
        const float* bf1_l  = bf1 + (size_t)l * 2048;
        const bf16*  W2_l   = w2b + (size_t)l * 256 * 2048;
        const float* bf2_l  = bf2 + (size_t)l * 256;
        const float* g2_l   = g2 + (size_t)l * 256;
        const float* be2_l  = be2 + (size_t)l * 256;

        // qkv = hb @ Wqkv^T + bqkv  (fp32 out)
        mfma_gemm<4, 4, 0, 0, 1, 0><<<(M / 128) * (768 / 128), 256, 0, stream>>>(
            hb, Wqkv_l, bqkv_l, nullptr, qkv, nullptr, M, 768, 256);
        // att = softmax(qk^T + seg-bias) v  (bf16 out)
        attn_kernel<<<BATCH * 8 * 32, 256, 0, stream>>>(qkv, attb, ind);
        // tmp = attb @ Wo^T + bo + h  (fp32 out)
        mfma_gemm<2, 2, 0, 1, 1, 0><<<(M / 64) * (256 / 64), 256, 0, stream>>>(
            attb, Wo_l, bo_l, h, tmp, nullptr, M, 256, 256);
        // h, hb = LN(tmp)
        ln_kernel<<<M, 256, 0, stream>>>(tmp, g1_l, be1_l, h, hb);
        // ffb = relu(hb @ W1^T + b1)  (bf16 out)
        mfma_gemm<4, 4, 1, 0, 0, 1><<<(M / 128) * (2048 / 128), 256, 0, stream>>>(
            hb, W1_l, bf1_l, nullptr, nullptr, ffb, M, 2048, 256);
        // tmp = ffb @ W2^T + b2 + h  (fp32 out)
        mfma_gemm<2, 2, 0, 1, 1, 0><<<(M / 64) * (256 / 64), 256, 0, stream>>>(
            ffb, W2_l, bf2_l, h, tmp, nullptr, M, 256, 2048);
        // h, hb = LN(tmp)
        ln_kernel<<<M, 256, 0, stream>>>(tmp, g2_l, be2_l, h, hb);
    }

    gather_kernel<<<BATCH, 256, 0, stream>>>(h, ind, out);
}

// Round 4
// 665.178 us; speedup vs baseline: 4.3482x; 1.8311x over previous
//
#include <hip/hip_runtime.h>
#include <hip/hip_bf16.h>
#include <math.h>

typedef __hip_bfloat16 bf16;
typedef short bf16x8 __attribute__((ext_vector_type(8)));
typedef float f32x4 __attribute__((ext_vector_type(4)));

#define D_MODEL 256
#define NTOK 1024
#define SEQ 1022
#define BATCH 4
#define NLAYER 6

// ---- async global->LDS 16B helper ----
__device__ inline void gload_lds16(const void* g, void* l) {
    __builtin_amdgcn_global_load_lds(
        (const __attribute__((address_space(1))) void*)g,
        (__attribute__((address_space(3))) void*)l, 16, 0, 0);
}

// ---------------- weight fp32 -> bf16 cast ----------------
__global__ __launch_bounds__(256) void cast_kernel(
    const float* __restrict__ in, bf16* __restrict__ out, int n)
{
    int i = (blockIdx.x * 256 + threadIdx.x) * 4;
    if (i >= n) return;
    f32x4 v = *(const f32x4*)(in + i);
    out[i + 0] = __float2bfloat16(v[0]);
    out[i + 1] = __float2bfloat16(v[1]);
    out[i + 2] = __float2bfloat16(v[2]);
    out[i + 3] = __float2bfloat16(v[3]);
}

// ---------------- embed ----------------
__global__ __launch_bounds__(256) void embed_kernel(
    const float* __restrict__ x, const float* __restrict__ cls1,
    const float* __restrict__ cls2, const int* __restrict__ ind,
    float* __restrict__ h, bf16* __restrict__ hb)
{
    int i = blockIdx.x * 256 + threadIdx.x;
    int d = i & 255;
    int pos = (i >> 8) & 1023;
    int b = i >> 18;
    int idx = ind[b];
    float v;
    if (pos == 0) v = cls1[d];
    else if (pos == idx + 1) v = cls2[d];
    else if (pos <= idx) v = x[(b * SEQ + pos - 1) * D_MODEL + d];
    else v = x[(b * SEQ + pos - 2) * D_MODEL + d];
    int p = d >> 1;
    float freq = expf(-(float)p * (logf(10000.0f) / 128.0f));
    float ang = (float)pos * freq;
    v += (d & 1) ? cosf(ang) : sinf(ang);
    h[i] = v;
    hb[i] = __float2bfloat16(v);
}

// ---------------- bf16 MFMA NT GEMM ----------------
template<int MR, int NR, int RELU, int HAS_RES, int WF32, int WBF16>
__global__ __launch_bounds__(256) void mfma_gemm(
    const bf16* __restrict__ A, const bf16* __restrict__ W,
    const float* __restrict__ bias, const float* __restrict__ R,
    float* __restrict__ Cf, bf16* __restrict__ Cb, int M, int N, int K)
{
    constexpr int BM = MR * 32, BN = NR * 32;
    constexpr int ACH = BM * 4;
    constexpr int BCH = BN * 4;
    __shared__ bf16 As[2][BM * 32];
    __shared__ bf16 Bs[2][BN * 32];
    const int ntile = N / BN;
    const int bx = blockIdx.x % ntile, by = blockIdx.x / ntile;
    const int row0 = by * BM, col0 = bx * BN;
    const int tid = threadIdx.x, lane = tid & 63, wave = tid >> 6;
    const int wr = wave >> 1, wc = wave & 1;
    const int l15 = lane & 15, l4 = lane >> 4;

    f32x4 acc[MR][NR];
    #pragma unroll
    for (int m = 0; m < MR; ++m)
        #pragma unroll
        for (int n = 0; n < NR; ++n) acc[m][n] = (f32x4)0.0f;

    const int nk = K / 32;

    auto stage = [&](int buf, int t) {
        const int k0 = t * 32;
        #pragma unroll
        for (int p = 0; p < ACH / 256; ++p) {
            const int cbase = p * 256 + wave * 64;
            const int chunk = cbase + lane;
            const int r = chunk >> 2, c = chunk & 3;
            gload_lds16(A + (size_t)(row0 + r) * K + k0 + c * 8, &As[buf][cbase * 8]);
        }
        #pragma unroll
        for (int p = 0; p < BCH / 256; ++p) {
            const int cbase = p * 256 + wave * 64;
            const int chunk = cbase + lane;
            const int r = chunk >> 2, c = chunk & 3;
            gload_lds16(W + (size_t)(col0 + r) * K + k0 + c * 8, &Bs[buf][cbase * 8]);
        }
    };

    stage(0, 0);
    __syncthreads();
    int cur = 0;
    for (int t = 0; t < nk; ++t) {
        if (t + 1 < nk) stage(cur ^ 1, t + 1);
        bf16x8 af[MR], bfr[NR];
        #pragma unroll
        for (int m = 0; m < MR; ++m)
            af[m] = *(const bf16x8*)&As[cur][(wr * MR * 16 + m * 16 + l15) * 32 + l4 * 8];
        #pragma unroll
        for (int n = 0; n < NR; ++n)
            bfr[n] = *(const bf16x8*)&Bs[cur][(wc * NR * 16 + n * 16 + l15) * 32 + l4 * 8];
        #pragma unroll
        for (int m = 0; m < MR; ++m)
            #pragma unroll
            for (int n = 0; n < NR; ++n)
                acc[m][n] = __builtin_amdgcn_mfma_f32_16x16x32_bf16(af[m], bfr[n], acc[m][n], 0, 0, 0);
        __syncthreads();
        cur ^= 1;
    }

    #pragma unroll
    for (int m = 0; m < MR; ++m) {
        #pragma unroll
        for (int n = 0; n < NR; ++n) {
            const int col = col0 + wc * NR * 16 + n * 16 + l15;
            const float bv = bias[col];
            #pragma unroll
            for (int r = 0; r < 4; ++r) {
                const int row = row0 + wr * MR * 16 + m * 16 + l4 * 4 + r;
                float v = acc[m][n][r] + bv;
                if (HAS_RES) v += R[(size_t)row * N + col];
                if (RELU) v = fmaxf(v, 0.0f);
                if (WF32) Cf[(size_t)row * N + col] = v;
                if (WBF16) Cb[(size_t)row * N + col] = __float2bfloat16(v);
            }
        }
    }
}

// ---------------- MFMA flash attention, two-segment block-diagonal mask ----------------
// grid: B*H*16 blocks; block = 64 q-rows of one (b,h); 4 waves, 16 q-rows/wave.
__global__ __launch_bounds__(256) void attn_mfma_kernel(
    const bf16* __restrict__ qkvb, bf16* __restrict__ att, const int* __restrict__ ind)
{
    __shared__ bf16 Qs[64][40];       // 80B stride: 16B aligned, 2-way max conflict
    __shared__ bf16 Ks[64][40];
    __shared__ short Vt[32][72];      // V transposed [d][k] — short: stores are BITWISE
    __shared__ bf16 Ps[4][16][72];    // per-wave P tile [q][k]
    const int qt = blockIdx.x & 15;
    const int hh = (blockIdx.x >> 4) & 7;
    const int b  = blockIdx.x >> 7;
    const int idx = ind[b];
    const int segEnd = NTOK - ind[4 + b];
    const int tid = threadIdx.x, lane = tid & 63, wave = tid >> 6;
    const int l15 = lane & 15, l4 = lane >> 4;
    const int q0 = qt * 64;
    const size_t tokbase = (size_t)b * NTOK;
    const float scale = 0.17677669529663687f;

    // stage Q tile [64][32]
    {
        const int row = tid >> 2, c = tid & 3;
        *(bf16x8*)&Qs[row][c * 8] =
            *(const bf16x8*)(qkvb + (tokbase + q0 + row) * 768 + hh * 32 + c * 8);
    }
    __syncthreads();
    const bf16x8 qfrag = *(const bf16x8*)&Qs[wave * 16 + l15][l4 * 8];

    f32x4 acc_o[2];
    acc_o[0] = (f32x4)0.0f; acc_o[1] = (f32x4)0.0f;
    float mrun[4], lrun[4];
    bool v1q[4], v2q[4];
    #pragma unroll
    for (int r = 0; r < 4; ++r) {
        mrun[r] = -1e30f; lrun[r] = 0.0f;
        const int qg = q0 + wave * 16 + l4 * 4 + r;
        v1q[r] = (qg <= idx);
        v2q[r] = (qg > idx) && (qg < segEnd);
    }

    const int kbeg = (q0 <= idx) ? 0 : (idx + 1);
    const int kend = (q0 + 63 > idx) ? segEnd : (idx + 1);

    for (int k0 = (kbeg & ~63); k0 < kend; k0 += 64) {
        __syncthreads();   // all waves done reading previous K/V
        {   // stage K tile [64][32]
            const int row = tid >> 2, c = tid & 3;
            *(bf16x8*)&Ks[row][c * 8] =
                *(const bf16x8*)(qkvb + (tokbase + k0 + row) * 768 + 256 + hh * 32 + c * 8);
        }
        {   // stage V transposed: wave w owns d-rows [w*8, w*8+8), lane = k (bitwise short copy)
            const bf16x8 vv =
                *(const bf16x8*)(qkvb + (tokbase + k0 + lane) * 768 + 512 + hh * 32 + wave * 8);
            #pragma unroll
            for (int j = 0; j < 8; ++j) Vt[wave * 8 + j][lane] = vv[j];
        }
        __syncthreads();

        // QK^T: 4 MFMAs -> S[16q x 64k], lane holds k=l15(+16kt), q=l4*4+r
        f32x4 sc[4];
        #pragma unroll
        for (int kt = 0; kt < 4; ++kt) {
            const bf16x8 kf = *(const bf16x8*)&Ks[kt * 16 + l15][l4 * 8];
            sc[kt] = __builtin_amdgcn_mfma_f32_16x16x32_bf16(qfrag, kf, (f32x4)0.0f, 0, 0, 0);
        }
        // mask + scale + row max
        float mloc[4] = {-1e30f, -1e30f, -1e30f, -1e30f};
        #pragma unroll
        for (int kt = 0; kt < 4; ++kt) {
            const int k = k0 + kt * 16 + l15;
            const bool v1k = (k <= idx);
            const bool v2k = (k > idx) && (k < segEnd);
            #pragma unroll
            for (int r = 0; r < 4; ++r) {
                const bool ok = (v1q[r] && v1k) || (v2q[r] && v2k);
                const float s = ok ? sc[kt][r] * scale : -1e30f;
                sc[kt][r] = s;
                mloc[r] = fmaxf(mloc[r], s);
            }
        }
        #pragma unroll
        for (int r = 0; r < 4; ++r) {
            mloc[r] = fmaxf(mloc[r], __shfl_xor(mloc[r], 1));
            mloc[r] = fmaxf(mloc[r], __shfl_xor(mloc[r], 2));
            mloc[r] = fmaxf(mloc[r], __shfl_xor(mloc[r], 4));
            mloc[r] = fmaxf(mloc[r], __shfl_xor(mloc[r], 8));
            const float mnew = fmaxf(mrun[r], mloc[r]);
            const float c = __expf(mrun[r] - mnew);
            mrun[r] = mnew;
            mloc[r] = c;            // reuse as corr
        }
        // exp + P write (bf16, wave-private LDS)
        float psum[4] = {0.0f, 0.0f, 0.0f, 0.0f};
        #pragma unroll
        for (int kt = 0; kt < 4; ++kt) {
            #pragma unroll
            for (int r = 0; r < 4; ++r) {
                const float s = sc[kt][r];
                const float p = (s > -5e29f) ? __expf(s - mrun[r]) : 0.0f;
                psum[r] += p;
                Ps[wave][l4 * 4 + r][kt * 16 + l15] = __float2bfloat16(p);
            }
        }
        #pragma unroll
        for (int r = 0; r < 4; ++r) {
            float ps = psum[r];
            ps += __shfl_xor(ps, 1); ps += __shfl_xor(ps, 2);
            ps += __shfl_xor(ps, 4); ps += __shfl_xor(ps, 8);
            lrun[r] = lrun[r] * mloc[r] + ps;
            acc_o[0][r] *= mloc[r];
            acc_o[1][r] *= mloc[r];
        }
        // PV: O[16q x 32d] += P[16q x 64k] @ V[64k x 32d]
        #pragma unroll
        for (int ks = 0; ks < 2; ++ks) {
            const bf16x8 pa = *(const bf16x8*)&Ps[wave][l15][ks * 32 + l4 * 8];
            #pragma unroll
            for (int dt = 0; dt < 2; ++dt) {
                const bf16x8 vb = *(const bf16x8*)&Vt[dt * 16 + l15][ks * 32 + l4 * 8];
                acc_o[dt] = __builtin_amdgcn_mfma_f32_16x16x32_bf16(pa, vb, acc_o[dt], 0, 0, 0);
            }
        }
    }

    #pragma unroll
    for (int r = 0; r < 4; ++r) {
        const float invl = (lrun[r] > 0.0f) ? (1.0f / lrun[r]) : 0.0f;
        const int qg = q0 + wave * 16 + l4 * 4 + r;
        bf16* op = att + (tokbase + qg) * 256 + hh * 32 + l15;
        op[0]  = __float2bfloat16(acc_o[0][r] * invl);
        op[16] = __float2bfloat16(acc_o[1][r] * invl);
    }
}

// ---------------- LayerNorm ----------------
__global__ __launch_bounds__(256) void ln_kernel(
    const float* __restrict__ X, const float* __restrict__ g,
    const float* __restrict__ bb, float* __restrict__ Y, bf16* __restrict__ Yb)
{
    __shared__ float red[8];
    int row = blockIdx.x;
    int tid = threadIdx.x;
    float x = X[row * 256 + tid];
    float s = x;
    #pragma unroll
    for (int off = 32; off >= 1; off >>= 1) s += __shfl_xor(s, off);
    if ((tid & 63) == 0) red[tid >> 6] = s;
    __syncthreads();
    float mu = (red[0] + red[1] + red[2] + red[3]) * (1.0f / 256.0f);
    float dv = x - mu;
    float s2 = dv * dv;
    #pragma unroll
    for (int off = 32; off >= 1; off >>= 1) s2 += __shfl_xor(s2, off);
    if ((tid & 63) == 0) red[4 + (tid >> 6)] = s2;
    __syncthreads();
    float var = (red[4] + red[5] + red[6] + red[7]) * (1.0f / 256.0f);
    float inv = 1.0f / sqrtf(var + 1e-5f);
    float y = dv * inv * g[tid] + bb[tid];
    Y[row * 256 + tid] = y;
    Yb[row * 256 + tid] = __float2bfloat16(y);
}

// ---------------- gather ----------------
__global__ __launch_bounds__(256) void gather_kernel(
    const float* __restrict__ h, const int* __restrict__ ind, float* __restrict__ out)
{
    int b = blockIdx.x;
    int tid = threadIdx.x;
    out[(b * 2 + 0) * 256 + tid] = h[(b * NTOK + 0) * 256 + tid];
    out[(b * 2 + 1) * 256 + tid] = h[(b * NTOK + ind[b] + 1) * 256 + tid];
}

extern "C" void kernel_launch(void* const* d_in, const int* in_sizes, int n_in,
                              void* d_out, int out_size, void* d_ws, size_t ws_size,
                              hipStream_t stream)
{
    const float* x    = (const float*)d_in[0];
    const int*   ind  = (const int*)d_in[2];
    const float* cls1 = (const float*)d_in[3];
    const float* cls2 = (const float*)d_in[4];
    const float* Wqkv = (const float*)d_in[5];
    const float* bqkv = (const float*)d_in[6];
    const float* Wo   = (const float*)d_in[7];
    const float* bo   = (const float*)d_in[8];
    const float* g1   = (const float*)d_in[9];
    const float* be1  = (const float*)d_in[10];
    const float* W1   = (const float*)d_in[11];
    const float* bf1  = (const float*)d_in[12];
    const float* W2   = (const float*)d_in[13];
    const float* bf2  = (const float*)d_in[14];
    const float* g2   = (const float*)d_in[15];
    const float* be2  = (const float*)d_in[16];
    float* out = (float*)d_out;

    // ---- workspace layout (51.4 MB) ----
    float* ws   = (float*)d_ws;
    float* h    = ws;                       // 1,048,576 f32
    float* tmp  = h + 1048576;              // 1,048,576 f32
    bf16* hb    = (bf16*)(tmp + 1048576);   // 1,048,576 bf16
    bf16* qkvb  = hb + 1048576;             // 3,145,728
    bf16* attb  = qkvb + 3145728;           // 1,048,576
    bf16* ffb   = attb + 1048576;           // 8,388,608
    bf16* wqkvb = ffb + 8388608;            // 1,179,648
    bf16* wob   = wqkvb + 1179648;          // 393,216
    bf16* w1b   = wob + 393216;             // 3,145,728
    bf16* w2b   = w1b + 3145728;            // 3,145,728

    const int M = BATCH * NTOK;             // 4096

    cast_kernel<<<1152, 256, 0, stream>>>(Wqkv, wqkvb, 1179648);
    cast_kernel<<<384,  256, 0, stream>>>(Wo,   wob,   393216);
    cast_kernel<<<3072, 256, 0, stream>>>(W1,   w1b,   3145728);
    cast_kernel<<<3072, 256, 0, stream>>>(W2,   w2b,   3145728);

    embed_kernel<<<M, 256, 0, stream>>>(x, cls1, cls2, ind, h, hb);

    for (int l = 0; l < NLAYER; ++l) {
        const bf16*  Wqkv_l = wqkvb + (size_t)l * 768 * 256;
        const float* bqkv_l = bqkv + (size_t)l * 768;
        const bf16*  Wo_l   = wob + (size_t)l * 256 * 256;
        const float* bo_l   = bo + (size_t)l * 256;
        const float* g1_l   = g1 + (size_t)l * 256;
        const float* be1_l  = be1 + (size_t)l * 256;
        const bf16*  W1_l   = w1b + (size_t)l * 2048 * 256;
        const float* bf1_l  = bf1 + (size_t)l * 2048;
        const bf16*  W2_l   = w2b + (size_t)l * 256 * 2048;
        const float* bf2_l  = bf2 + (size_t)l * 256;
        const float* g2_l   = g2 + (size_t)l * 256;
        const float* be2_l  = be2 + (size_t)l * 256;

        // qkvb = hb @ Wqkv^T + bqkv  (bf16 out)
        mfma_gemm<4, 4, 0, 0, 0, 1><<<(M / 128) * (768 / 128), 256, 0, stream>>>(
            hb, Wqkv_l, bqkv_l, nullptr, nullptr, qkvb, M, 768, 256);
        // attb = softmax(qk^T + seg-bias) v  (bf16 out)
        attn_mfma_kernel<<<BATCH * 8 * 16, 256, 0, stream>>>(qkvb, attb, ind);
        // tmp = attb @ Wo^T + bo + h  (fp32 out)
        mfma_gemm<2, 2, 0, 1, 1, 0><<<(M / 64) * (256 / 64), 256, 0, stream>>>(
            attb, Wo_l, bo_l, h, tmp, nullptr, M, 256, 256);
        ln_kernel<<<M, 256, 0, stream>>>(tmp, g1_l, be1_l, h, hb);
        // ffb = relu(hb @ W1^T + b1)  (bf16 out)
        mfma_gemm<4, 4, 1, 0, 0, 1><<<(M / 128) * (2048 / 128), 256, 0, stream>>>(
            hb, W1_l, bf1_l, nullptr, nullptr, ffb, M, 2048, 256);
        // tmp = ffb @ W2^T + b2 + h  (fp32 out)
        mfma_gemm<2, 2, 0, 1, 1, 0><<<(M / 64) * (256 / 64), 256, 0, stream>>>(
            ffb, W2_l, bf2_l, h, tmp, nullptr, M, 256, 2048);
        ln_kernel<<<M, 256, 0, stream>>>(tmp, g2_l, be2_l, h, hb);
    }

    gather_kernel<<<BATCH, 256, 0, stream>>>(h, ind, out);
}

// Round 5
// 591.634 us; speedup vs baseline: 4.8887x; 1.1243x over previous
//
#include <hip/hip_runtime.h>
#include <hip/hip_bf16.h>
#include <math.h>

typedef __hip_bfloat16 bf16;
typedef short bf16x8 __attribute__((ext_vector_type(8)));
typedef float f32x4 __attribute__((ext_vector_type(4)));

#define D_MODEL 256
#define NTOK 1024
#define SEQ 1022
#define BATCH 4
#define NLAYER 6

// ---- async global->LDS 16B helper ----
__device__ inline void gload_lds16(const void* g, void* l) {
    __builtin_amdgcn_global_load_lds(
        (const __attribute__((address_space(1))) void*)g,
        (__attribute__((address_space(3))) void*)l, 16, 0, 0);
}

// ---------------- weight fp32 -> bf16 cast ----------------
__global__ __launch_bounds__(256) void cast_kernel(
    const float* __restrict__ in, bf16* __restrict__ out, int n)
{
    int i = (blockIdx.x * 256 + threadIdx.x) * 4;
    if (i >= n) return;
    f32x4 v = *(const f32x4*)(in + i);
    out[i + 0] = __float2bfloat16(v[0]);
    out[i + 1] = __float2bfloat16(v[1]);
    out[i + 2] = __float2bfloat16(v[2]);
    out[i + 3] = __float2bfloat16(v[3]);
}

// ---------------- embed ----------------
__global__ __launch_bounds__(256) void embed_kernel(
    const float* __restrict__ x, const float* __restrict__ cls1,
    const float* __restrict__ cls2, const int* __restrict__ ind,
    float* __restrict__ h, bf16* __restrict__ hb)
{
    int i = blockIdx.x * 256 + threadIdx.x;
    int d = i & 255;
    int pos = (i >> 8) & 1023;
    int b = i >> 18;
    int idx = ind[b];
    float v;
    if (pos == 0) v = cls1[d];
    else if (pos == idx + 1) v = cls2[d];
    else if (pos <= idx) v = x[(b * SEQ + pos - 1) * D_MODEL + d];
    else v = x[(b * SEQ + pos - 2) * D_MODEL + d];
    int p = d >> 1;
    float freq = expf(-(float)p * (logf(10000.0f) / 128.0f));
    float ang = (float)pos * freq;
    v += (d & 1) ? cosf(ang) : sinf(ang);
    h[i] = v;
    hb[i] = __float2bfloat16(v);
}

// ---------------- bf16 MFMA NT GEMM ----------------
// WVT: epilogue redirect for cols>=512 -> vT[(b*8+h)*32+d][tok]  (pre-transposed V)
template<int MR, int NR, int RELU, int HAS_RES, int WF32, int WBF16, int WVT>
__global__ __launch_bounds__(256) void mfma_gemm(
    const bf16* __restrict__ A, const bf16* __restrict__ W,
    const float* __restrict__ bias, const float* __restrict__ R,
    float* __restrict__ Cf, bf16* __restrict__ Cb, bf16* __restrict__ vTb,
    int M, int N, int K)
{
    constexpr int BM = MR * 32, BN = NR * 32;
    constexpr int ACH = BM * 4;
    constexpr int BCH = BN * 4;
    __shared__ bf16 As[2][BM * 32];
    __shared__ bf16 Bs[2][BN * 32];
    const int ntile = N / BN;
    const int bx = blockIdx.x % ntile, by = blockIdx.x / ntile;
    const int row0 = by * BM, col0 = bx * BN;
    const int tid = threadIdx.x, lane = tid & 63, wave = tid >> 6;
    const int wr = wave >> 1, wc = wave & 1;
    const int l15 = lane & 15, l4 = lane >> 4;

    f32x4 acc[MR][NR];
    #pragma unroll
    for (int m = 0; m < MR; ++m)
        #pragma unroll
        for (int n = 0; n < NR; ++n) acc[m][n] = (f32x4)0.0f;

    const int nk = K / 32;

    auto stage = [&](int buf, int t) {
        const int k0 = t * 32;
        #pragma unroll
        for (int p = 0; p < ACH / 256; ++p) {
            const int cbase = p * 256 + wave * 64;
            const int chunk = cbase + lane;
            const int r = chunk >> 2, c = chunk & 3;
            gload_lds16(A + (size_t)(row0 + r) * K + k0 + c * 8, &As[buf][cbase * 8]);
        }
        #pragma unroll
        for (int p = 0; p < BCH / 256; ++p) {
            const int cbase = p * 256 + wave * 64;
            const int chunk = cbase + lane;
            const int r = chunk >> 2, c = chunk & 3;
            gload_lds16(W + (size_t)(col0 + r) * K + k0 + c * 8, &Bs[buf][cbase * 8]);
        }
    };

    stage(0, 0);
    __syncthreads();
    int cur = 0;
    for (int t = 0; t < nk; ++t) {
        if (t + 1 < nk) stage(cur ^ 1, t + 1);
        bf16x8 af[MR], bfr[NR];
        #pragma unroll
        for (int m = 0; m < MR; ++m)
            af[m] = *(const bf16x8*)&As[cur][(wr * MR * 16 + m * 16 + l15) * 32 + l4 * 8];
        #pragma unroll
        for (int n = 0; n < NR; ++n)
            bfr[n] = *(const bf16x8*)&Bs[cur][(wc * NR * 16 + n * 16 + l15) * 32 + l4 * 8];
        #pragma unroll
        for (int m = 0; m < MR; ++m)
            #pragma unroll
            for (int n = 0; n < NR; ++n)
                acc[m][n] = __builtin_amdgcn_mfma_f32_16x16x32_bf16(af[m], bfr[n], acc[m][n], 0, 0, 0);
        __syncthreads();
        cur ^= 1;
    }

    #pragma unroll
    for (int m = 0; m < MR; ++m) {
        #pragma unroll
        for (int n = 0; n < NR; ++n) {
            const int col = col0 + wc * NR * 16 + n * 16 + l15;
            const float bv = bias[col];
            #pragma unroll
            for (int r = 0; r < 4; ++r) {
                const int row = row0 + wr * MR * 16 + m * 16 + l4 * 4 + r;
                float v = acc[m][n][r] + bv;
                if (HAS_RES) v += R[(size_t)row * N + col];
                if (RELU) v = fmaxf(v, 0.0f);
                if (WF32) Cf[(size_t)row * N + col] = v;
                if (WBF16) {
                    if (WVT && col >= 512) {
                        const int hh = (col >> 5) - 16, d = col & 31;
                        const int bb = row >> 10, tt = row & 1023;
                        vTb[(((size_t)bb * 8 + hh) * 32 + d) * 1024 + tt] = __float2bfloat16(v);
                    } else {
                        Cb[(size_t)row * N + col] = __float2bfloat16(v);
                    }
                }
            }
        }
    }
}

// ---------------- barrier-free MFMA flash attention ----------------
// grid: B*H*16 blocks, 4 waves; each WAVE independently owns a 16-q strip.
// Q/K fragments loaded straight from global; V from pre-transposed vT.
// Only P goes through wave-private LDS (no __syncthreads anywhere).
__global__ __launch_bounds__(256) void attn_mfma_kernel(
    const bf16* __restrict__ qkvb, const bf16* __restrict__ vT,
    bf16* __restrict__ att, const int* __restrict__ ind)
{
    __shared__ bf16 Ps[4][16][72];
    const int qt = blockIdx.x & 15;
    const int hh = (blockIdx.x >> 4) & 7;
    const int b  = blockIdx.x >> 7;
    const int idx = ind[b];
    const int segEnd = NTOK - ind[4 + b];
    const int tid = threadIdx.x, lane = tid & 63, wave = tid >> 6;
    const int l15 = lane & 15, l4 = lane >> 4;
    const int q0 = qt * 64 + wave * 16;          // wave-private 16-q strip
    const size_t tokbase = (size_t)b * NTOK;
    const bf16* vTh = vT + (((size_t)b * 8 + hh) * 32) * 1024;
    const float scale = 0.17677669529663687f;

    // Q A-fragment: lane l15 = q-row, l4*8 = d-chunk  (direct 16B global load)
    const bf16x8 qfrag = *(const bf16x8*)(qkvb + (tokbase + q0 + l15) * 768 + hh * 32 + l4 * 8);

    f32x4 acc_o[2];
    acc_o[0] = (f32x4)0.0f; acc_o[1] = (f32x4)0.0f;
    float mrun[4], lrun[4];
    bool v1q[4], v2q[4];
    #pragma unroll
    for (int r = 0; r < 4; ++r) {
        mrun[r] = -1e30f; lrun[r] = 0.0f;
        const int qg = q0 + l4 * 4 + r;
        v1q[r] = (qg <= idx);
        v2q[r] = (qg > idx) && (qg < segEnd);
    }

    const int kbeg = (q0 <= idx) ? 0 : (idx + 1);
    const int kend = (q0 + 15 > idx) ? segEnd : (idx + 1);

    for (int k0 = (kbeg & ~63); k0 < kend; k0 += 64) {
        // QK^T: B-fragment = K rows direct from global
        f32x4 sc[4];
        #pragma unroll
        for (int kt = 0; kt < 4; ++kt) {
            const bf16x8 kf = *(const bf16x8*)
                (qkvb + (tokbase + k0 + kt * 16 + l15) * 768 + 256 + hh * 32 + l4 * 8);
            sc[kt] = __builtin_amdgcn_mfma_f32_16x16x32_bf16(qfrag, kf, (f32x4)0.0f, 0, 0, 0);
        }
        // mask + scale + row max (row q = l4*4+r, cols k = kt*16+l15)
        float mloc[4] = {-1e30f, -1e30f, -1e30f, -1e30f};
        #pragma unroll
        for (int kt = 0; kt < 4; ++kt) {
            const int k = k0 + kt * 16 + l15;
            const bool v1k = (k <= idx);
            const bool v2k = (k > idx) && (k < segEnd);
            #pragma unroll
            for (int r = 0; r < 4; ++r) {
                const bool ok = (v1q[r] && v1k) || (v2q[r] && v2k);
                const float s = ok ? sc[kt][r] * scale : -1e30f;
                sc[kt][r] = s;
                mloc[r] = fmaxf(mloc[r], s);
            }
        }
        #pragma unroll
        for (int r = 0; r < 4; ++r) {
            mloc[r] = fmaxf(mloc[r], __shfl_xor(mloc[r], 1));
            mloc[r] = fmaxf(mloc[r], __shfl_xor(mloc[r], 2));
            mloc[r] = fmaxf(mloc[r], __shfl_xor(mloc[r], 4));
            mloc[r] = fmaxf(mloc[r], __shfl_xor(mloc[r], 8));
            const float mnew = fmaxf(mrun[r], mloc[r]);
            const float c = __expf(mrun[r] - mnew);
            mrun[r] = mnew;
            mloc[r] = c;            // reuse as corr
        }
        // exp + P write (wave-private LDS; in-wave RAW handled by lgkmcnt)
        float psum[4] = {0.0f, 0.0f, 0.0f, 0.0f};
        #pragma unroll
        for (int kt = 0; kt < 4; ++kt) {
            #pragma unroll
            for (int r = 0; r < 4; ++r) {
                const float s = sc[kt][r];
                const float p = (s > -5e29f) ? __expf(s - mrun[r]) : 0.0f;
                psum[r] += p;
                Ps[wave][l4 * 4 + r][kt * 16 + l15] = __float2bfloat16(p);
            }
        }
        #pragma unroll
        for (int r = 0; r < 4; ++r) {
            float ps = psum[r];
            ps += __shfl_xor(ps, 1); ps += __shfl_xor(ps, 2);
            ps += __shfl_xor(ps, 4); ps += __shfl_xor(ps, 8);
            lrun[r] = lrun[r] * mloc[r] + ps;
            acc_o[0][r] *= mloc[r];
            acc_o[1][r] *= mloc[r];
        }
        // PV: A = P (LDS), B = V^T rows direct from global (vT)
        #pragma unroll
        for (int ks = 0; ks < 2; ++ks) {
            const bf16x8 pa = *(const bf16x8*)&Ps[wave][l15][ks * 32 + l4 * 8];
            #pragma unroll
            for (int dt = 0; dt < 2; ++dt) {
                const bf16x8 vb = *(const bf16x8*)
                    (vTh + (size_t)(dt * 16 + l15) * 1024 + k0 + ks * 32 + l4 * 8);
                acc_o[dt] = __builtin_amdgcn_mfma_f32_16x16x32_bf16(pa, vb, acc_o[dt], 0, 0, 0);
            }
        }
    }

    #pragma unroll
    for (int r = 0; r < 4; ++r) {
        const float invl = (lrun[r] > 0.0f) ? (1.0f / lrun[r]) : 0.0f;
        const int qg = q0 + l4 * 4 + r;
        bf16* op = att + (tokbase + qg) * 256 + hh * 32 + l15;
        op[0]  = __float2bfloat16(acc_o[0][r] * invl);
        op[16] = __float2bfloat16(acc_o[1][r] * invl);
    }
}

// ---------------- LayerNorm: one wave per row, shuffle-only ----------------
__global__ __launch_bounds__(256) void ln_kernel(
    const float* __restrict__ X, const float* __restrict__ g,
    const float* __restrict__ bb, float* __restrict__ Y, bf16* __restrict__ Yb)
{
    const int row = blockIdx.x * 4 + (threadIdx.x >> 6);
    const int lane = threadIdx.x & 63;
    const f32x4 xv = *(const f32x4*)(X + (size_t)row * 256 + lane * 4);
    float s = (xv[0] + xv[1]) + (xv[2] + xv[3]);
    #pragma unroll
    for (int off = 32; off >= 1; off >>= 1) s += __shfl_xor(s, off);
    const float mu = s * (1.0f / 256.0f);
    f32x4 dv;
    float s2 = 0.0f;
    #pragma unroll
    for (int e = 0; e < 4; ++e) { dv[e] = xv[e] - mu; s2 += dv[e] * dv[e]; }
    #pragma unroll
    for (int off = 32; off >= 1; off >>= 1) s2 += __shfl_xor(s2, off);
    const float inv = 1.0f / sqrtf(s2 * (1.0f / 256.0f) + 1e-5f);
    const f32x4 gv = *(const f32x4*)(g + lane * 4);
    const f32x4 bv = *(const f32x4*)(bb + lane * 4);
    f32x4 y;
    bf16x8 yb2;     // only low 4 used via short4 store
    short sh[4];
    #pragma unroll
    for (int e = 0; e < 4; ++e) {
        y[e] = dv[e] * inv * gv[e] + bv[e];
        sh[e] = __builtin_bit_cast(short, __float2bfloat16(y[e]));
    }
    *(f32x4*)(Y + (size_t)row * 256 + lane * 4) = y;
    typedef short short4v __attribute__((ext_vector_type(4)));
    short4v pack; pack[0] = sh[0]; pack[1] = sh[1]; pack[2] = sh[2]; pack[3] = sh[3];
    *(short4v*)((short*)Yb + (size_t)row * 256 + lane * 4) = pack;
    (void)yb2;
}

// ---------------- gather ----------------
__global__ __launch_bounds__(256) void gather_kernel(
    const float* __restrict__ h, const int* __restrict__ ind, float* __restrict__ out)
{
    int b = blockIdx.x;
    int tid = threadIdx.x;
    out[(b * 2 + 0) * 256 + tid] = h[(b * NTOK + 0) * 256 + tid];
    out[(b * 2 + 1) * 256 + tid] = h[(b * NTOK + ind[b] + 1) * 256 + tid];
}

extern "C" void kernel_launch(void* const* d_in, const int* in_sizes, int n_in,
                              void* d_out, int out_size, void* d_ws, size_t ws_size,
                              hipStream_t stream)
{
    const float* x    = (const float*)d_in[0];
    const int*   ind  = (const int*)d_in[2];
    const float* cls1 = (const float*)d_in[3];
    const float* cls2 = (const float*)d_in[4];
    const float* Wqkv = (const float*)d_in[5];
    const float* bqkv = (const float*)d_in[6];
    const float* Wo   = (const float*)d_in[7];
    const float* bo   = (const float*)d_in[8];
    const float* g1   = (const float*)d_in[9];
    const float* be1  = (const float*)d_in[10];
    const float* W1   = (const float*)d_in[11];
    const float* bf1  = (const float*)d_in[12];
    const float* W2   = (const float*)d_in[13];
    const float* bf2  = (const float*)d_in[14];
    const float* g2   = (const float*)d_in[15];
    const float* be2  = (const float*)d_in[16];
    float* out = (float*)d_out;

    // ---- workspace layout ----
    float* ws   = (float*)d_ws;
    float* h    = ws;                       // 1,048,576 f32
    float* tmp  = h + 1048576;              // 1,048,576 f32
    bf16* hb    = (bf16*)(tmp + 1048576);   // 1,048,576 bf16
    bf16* qkvb  = hb + 1048576;             // 3,145,728
    bf16* vTb   = qkvb + 3145728;           // 1,048,576  (V transposed per (b,h,d))
    bf16* attb  = vTb + 1048576;            // 1,048,576
    bf16* ffb   = attb + 1048576;           // 8,388,608
    bf16* wqkvb = ffb + 8388608;            // 1,179,648
    bf16* wob   = wqkvb + 1179648;          // 393,216
    bf16* w1b   = wob + 393216;             // 3,145,728
    bf16* w2b   = w1b + 3145728;            // 3,145,728

    const int M = BATCH * NTOK;             // 4096

    cast_kernel<<<1152, 256, 0, stream>>>(Wqkv, wqkvb, 1179648);
    cast_kernel<<<384,  256, 0, stream>>>(Wo,   wob,   393216);
    cast_kernel<<<3072, 256, 0, stream>>>(W1,   w1b,   3145728);
    cast_kernel<<<3072, 256, 0, stream>>>(W2,   w2b,   3145728);

    embed_kernel<<<M, 256, 0, stream>>>(x, cls1, cls2, ind, h, hb);

    for (int l = 0; l < NLAYER; ++l) {
        const bf16*  Wqkv_l = wqkvb + (size_t)l * 768 * 256;
        const float* bqkv_l = bqkv + (size_t)l * 768;
        const bf16*  Wo_l   = wob + (size_t)l * 256 * 256;
        const float* bo_l   = bo + (size_t)l * 256;
        const float* g1_l   = g1 + (size_t)l * 256;
        const float* be1_l  = be1 + (size_t)l * 256;
        const bf16*  W1_l   = w1b + (size_t)l * 2048 * 256;
        const float* bf1_l  = bf1 + (size_t)l * 2048;
        const bf16*  W2_l   = w2b + (size_t)l * 256 * 2048;
        const float* bf2_l  = bf2 + (size_t)l * 256;
        const float* g2_l   = g2 + (size_t)l * 256;
        const float* be2_l  = be2 + (size_t)l * 256;

        // qkvb = hb @ Wqkv^T + bqkv ; V-part redirected to vT layout
        mfma_gemm<4, 4, 0, 0, 0, 1, 1><<<(M / 128) * (768 / 128), 256, 0, stream>>>(
            hb, Wqkv_l, bqkv_l, nullptr, nullptr, qkvb, vTb, M, 768, 256);
        // attb = softmax(qk^T + seg-bias) v   (barrier-free)
        attn_mfma_kernel<<<BATCH * 8 * 16, 256, 0, stream>>>(qkvb, vTb, attb, ind);
        // tmp = attb @ Wo^T + bo + h  (fp32 out)
        mfma_gemm<2, 2, 0, 1, 1, 0, 0><<<(M / 64) * (256 / 64), 256, 0, stream>>>(
            attb, Wo_l, bo_l, h, tmp, nullptr, nullptr, M, 256, 256);
        ln_kernel<<<M / 4, 256, 0, stream>>>(tmp, g1_l, be1_l, h, hb);
        // ffb = relu(hb @ W1^T + b1)  (bf16 out)
        mfma_gemm<4, 4, 1, 0, 0, 1, 0><<<(M / 128) * (2048 / 128), 256, 0, stream>>>(
            hb, W1_l, bf1_l, nullptr, nullptr, ffb, nullptr, M, 2048, 256);
        // tmp = ffb @ W2^T + b2 + h  (fp32 out)
        mfma_gemm<2, 2, 0, 1, 1, 0, 0><<<(M / 64) * (256 / 64), 256, 0, stream>>>(
            ffb, W2_l, bf2_l, h, tmp, nullptr, nullptr, M, 256, 2048);
        ln_kernel<<<M / 4, 256, 0, stream>>>(tmp, g2_l, be2_l, h, hb);
    }

    gather_kernel<<<BATCH, 256, 0, stream>>>(h, ind, out);
}